// Round 2
// baseline (557.324 us; speedup 1.0000x reference)
//
#include <hip/hip_runtime.h>
#include <hip/hip_bf16.h>

// Problem constants
constexpr int Lq = 2048;   // sequence length
constexpr int Dm = 1024;   // model dim
constexpr int Hh = 16;     // heads
constexpr int HD = 64;     // head dim

typedef __bf16 v8bf __attribute__((ext_vector_type(8)));
typedef short  v4s  __attribute__((ext_vector_type(4)));
typedef float  v4f  __attribute__((ext_vector_type(4)));

#define DEV static __device__ __forceinline__

DEV short f2bf(float f) {
  return (short)__builtin_bit_cast(unsigned short, __float2bfloat16(f));
}

DEV v4f MFMA(v8bf a, v8bf b, v4f c) {
  return __builtin_amdgcn_mfma_f32_16x16x32_bf16(a, b, c, 0, 0, 0);
}

// ---------------------------------------------------------------------------
// GEMM: C[i,o] = sum_k A[i,k] * W[o,k]  (+bias etc. per MODE epilogue)
// A: fp32 (MODE 0..3) or bf16 (MODE 4), row-major MxK. W: fp32 NxK. K=N=1024.
// 128x128 block tile, 4 waves (each 64x64), BK=32, reg-staged LDS (padded).
// MODE 0: Q  -> writes Qu = y+bq+u and Qv = y+bq+v into (B,H,L,HD) bf16
// MODE 1: K  -> Kb (B,H,L,HD) bf16
// MODE 2: V  -> Vt (B,H,HD,L) bf16 (transposed)
// MODE 3: P  -> Pb (H,L,HD)  bf16 (no bias)
// MODE 4: O  -> d_out fp32 (B*L, D) = A@Wo^T + bo
// ---------------------------------------------------------------------------
template<int MODE>
__launch_bounds__(256)
__global__ void gemm_bt(const void* __restrict__ Aptr,
                        const float* __restrict__ W,
                        const float* __restrict__ bias,
                        const float* __restrict__ ubias,
                        const float* __restrict__ vbias,
                        void* __restrict__ out0,
                        void* __restrict__ out1)
{
  __shared__ short As[128][40];  // +8 pad: conflict-free ds_read_b128
  __shared__ short Bs[128][40];

  const int tid  = threadIdx.x;
  const int lane = tid & 63;
  const int wave = tid >> 6;
  const int lr   = lane & 15;
  const int lg   = lane >> 4;
  const int row0 = blockIdx.y * 128;
  const int col0 = blockIdx.x * 128;
  const int wr   = (wave >> 1) * 64;
  const int wc   = (wave & 1) * 64;

  v4f acc[4][4] = {};

  for (int k0 = 0; k0 < Dm; k0 += 32) {
    __syncthreads();
    // ---- stage A tile (128x32) ----
    if (MODE == 4) {
      const short* A = (const short*)Aptr;
      #pragma unroll
      for (int i = 0; i < 2; ++i) {
        int c = tid + i * 256;           // 512 chunks of 8 bf16
        int row = c >> 2, col = (c & 3) * 8;
        *(v8bf*)(&As[row][col]) =
            *(const v8bf*)(A + (size_t)(row0 + row) * Dm + k0 + col);
      }
    } else {
      const float* A = (const float*)Aptr;
      #pragma unroll
      for (int i = 0; i < 4; ++i) {
        int c = tid + i * 256;           // 1024 chunks of 4 fp32
        int row = c >> 3, col = (c & 7) * 4;
        float4 v = *(const float4*)(A + (size_t)(row0 + row) * Dm + k0 + col);
        v4s w; w[0] = f2bf(v.x); w[1] = f2bf(v.y); w[2] = f2bf(v.z); w[3] = f2bf(v.w);
        *(v4s*)(&As[row][col]) = w;
      }
    }
    // ---- stage B tile (128x32) from W fp32 ----
    #pragma unroll
    for (int i = 0; i < 4; ++i) {
      int c = tid + i * 256;
      int row = c >> 3, col = (c & 7) * 4;
      float4 v = *(const float4*)(W + (size_t)(col0 + row) * Dm + k0 + col);
      v4s w; w[0] = f2bf(v.x); w[1] = f2bf(v.y); w[2] = f2bf(v.z); w[3] = f2bf(v.w);
      *(v4s*)(&Bs[row][col]) = w;
    }
    __syncthreads();

    v8bf af[4], bfr[4];
    #pragma unroll
    for (int sm = 0; sm < 4; ++sm)
      af[sm] = *(const v8bf*)(&As[wr + sm * 16 + lr][lg * 8]);
    #pragma unroll
    for (int sn = 0; sn < 4; ++sn)
      bfr[sn] = *(const v8bf*)(&Bs[wc + sn * 16 + lr][lg * 8]);
    #pragma unroll
    for (int sm = 0; sm < 4; ++sm)
      #pragma unroll
      for (int sn = 0; sn < 4; ++sn)
        acc[sm][sn] = MFMA(af[sm], bfr[sn], acc[sm][sn]);
  }

  // ---- epilogue (C frag: col = lane&15, row = (lane>>4)*4 + r) ----
  #pragma unroll
  for (int sm = 0; sm < 4; ++sm) {
    #pragma unroll
    for (int sn = 0; sn < 4; ++sn) {
      #pragma unroll
      for (int r = 0; r < 4; ++r) {
        int i = row0 + wr + sm * 16 + lg * 4 + r;
        int o = col0 + wc + sn * 16 + lr;
        float val = acc[sm][sn][r];
        if (MODE == 0) {
          val += bias[o];
          int b = i >> 11, l = i & 2047;
          int h = o >> 6,  hd = o & 63;
          size_t idx = (((size_t)(b * Hh + h)) * Lq + l) * HD + hd;
          ((short*)out0)[idx] = f2bf(val + ubias[o]);
          ((short*)out1)[idx] = f2bf(val + vbias[o]);
        } else if (MODE == 1) {
          val += bias[o];
          int b = i >> 11, l = i & 2047;
          int h = o >> 6,  hd = o & 63;
          size_t idx = (((size_t)(b * Hh + h)) * Lq + l) * HD + hd;
          ((short*)out0)[idx] = f2bf(val);
        } else if (MODE == 2) {
          val += bias[o];
          int b = i >> 11, l = i & 2047;
          int h = o >> 6,  hd = o & 63;
          size_t idx = (((size_t)(b * Hh + h)) * HD + hd) * Lq + l;
          ((short*)out0)[idx] = f2bf(val);
        } else if (MODE == 3) {
          int h = o >> 6, hd = o & 63;
          size_t idx = ((size_t)h * Lq + i) * HD + hd;
          ((short*)out0)[idx] = f2bf(val);
        } else {
          ((float*)out0)[(size_t)i * Dm + o] = val + bias[o];
        }
      }
    }
  }
}

// ---------------------------------------------------------------------------
// Fused rel-pos flash attention.
// grid (L/64, B*H), block 256 (4 waves, each owns a 16-row q-strip).
// rel_shift closed form:
//   k <= q   : bd[q,   L-1-q+k]
//   k == q+1 : 0
//   k >  q+1 : bd[q+1, k-q-2]        (row-wrap artifact of the reshape trick)
// T1/T2 = banded (Qv @ P_band^T) MFMAs; per-row constant shift resolved by
// in-group __shfl.
// ---------------------------------------------------------------------------
__launch_bounds__(256)
__global__ void attn_kernel(const short* __restrict__ Qu,
                            const short* __restrict__ Qv,
                            const short* __restrict__ Kb,
                            const short* __restrict__ Vt,
                            const short* __restrict__ Pb,
                            short* __restrict__ AO)
{
  __shared__ short Ks[64][72];      // K tile: rows=k, cols=hd
  __shared__ short Vs[64][72];      // V^T tile: rows=hd, cols=k
  __shared__ short Ps[4][16][72];   // per-wave softmax probs (bf16)

  const int tid  = threadIdx.x;
  const int lane = tid & 63;
  const int wave = tid >> 6;
  const int lr   = lane & 15;
  const int lg   = lane >> 4;
  const int bh   = blockIdx.y;          // b*H + h
  const int h    = bh & (Hh - 1);
  const int Q0   = blockIdx.x * 64;
  const int q0   = Q0 + wave * 16;

  const short* Qu_bh = Qu + (size_t)bh * Lq * HD;
  const short* Qv_bh = Qv + (size_t)bh * Lq * HD;
  const short* Kb_bh = Kb + (size_t)bh * Lq * HD;
  const short* Vt_bh = Vt + (size_t)bh * HD * Lq;
  const short* Pb_h  = Pb + (size_t)h * Lq * HD;

  // Q fragments (A operand): lane holds row (q0+lr), k = kk*32 + lg*8 + e
  v8bf qu[2], qv1[2], qv2[2];
  {
    int q  = q0 + lr;
    int q2 = (q + 1 < Lq) ? q + 1 : Lq - 1;   // clamped row never selected
    #pragma unroll
    for (int kk = 0; kk < 2; ++kk) {
      qu[kk]  = *(const v8bf*)(Qu_bh + (size_t)q  * HD + kk * 32 + lg * 8);
      qv1[kk] = *(const v8bf*)(Qv_bh + (size_t)q  * HD + kk * 32 + lg * 8);
      qv2[kk] = *(const v8bf*)(Qv_bh + (size_t)q2 * HD + kk * 32 + lg * 8);
    }
  }

  float m_r[4], l_r[4];
  v4f o_acc[4];
  #pragma unroll
  for (int r = 0; r < 4; ++r) { m_r[r] = -1e30f; l_r[r] = 0.f; }
  #pragma unroll
  for (int n = 0; n < 4; ++n) o_acc[n] = v4f{0.f, 0.f, 0.f, 0.f};

  for (int ktile = 0; ktile < Lq / 64; ++ktile) {
    const int k0 = ktile * 64;
    __syncthreads();
    // ---- stage K (64x64) and V^T (64x64) tiles ----
    #pragma unroll
    for (int i = 0; i < 2; ++i) {
      int c = tid + i * 256;
      int row = c >> 3, col = (c & 7) * 8;
      *(v8bf*)(&Ks[row][col]) =
          *(const v8bf*)(Kb_bh + (size_t)(k0 + row) * HD + col);
    }
    #pragma unroll
    for (int i = 0; i < 2; ++i) {
      int c = tid + i * 256;
      int row = c >> 3, col = (c & 7) * 8;
      *(v8bf*)(&Vs[row][col]) =
          *(const v8bf*)(Vt_bh + (size_t)row * Lq + k0 + col);
    }
    __syncthreads();

    // ---- ac = Qu @ K^T  (16 x 64) ----
    v4f s[4];
    #pragma unroll
    for (int kt4 = 0; kt4 < 4; ++kt4) {
      v4f a = v4f{0.f, 0.f, 0.f, 0.f};
      #pragma unroll
      for (int kk = 0; kk < 2; ++kk) {
        v8bf kb = *(const v8bf*)(&Ks[kt4 * 16 + lr][kk * 32 + lg * 8]);
        a = MFMA(qu[kk], kb, a);
      }
      s[kt4] = a;
    }

    // ---- banded bd: T1 (rows q), T2 (rows q+1); band col c = dk-dq+15 ----
    const bool needT1 = (k0 <= q0 + 15);
    const bool needT2 = (k0 + 63 >= q0 + 2);
    const int jb1 = (Lq - 1) - q0 + k0 - 15;
    const int jb2 = k0 - q0 - 17;
    v4f t1[5] = {}, t2[5] = {};
    if (needT1) {
      #pragma unroll
      for (int n = 0; n < 5; ++n) {
        int j = jb1 + n * 16 + lr;
        j = j < 0 ? 0 : (j > Lq - 1 ? Lq - 1 : j);  // clamped rows never selected
        v4f a = v4f{0.f, 0.f, 0.f, 0.f};
        #pragma unroll
        for (int kk = 0; kk < 2; ++kk) {
          v8bf pb = *(const v8bf*)(Pb_h + (size_t)j * HD + kk * 32 + lg * 8);
          a = MFMA(qv1[kk], pb, a);
        }
        t1[n] = a;
      }
    }
    if (needT2) {
      #pragma unroll
      for (int n = 0; n < 5; ++n) {
        int j = jb2 + n * 16 + lr;
        j = j < 0 ? 0 : (j > Lq - 1 ? Lq - 1 : j);
        v4f a = v4f{0.f, 0.f, 0.f, 0.f};
        #pragma unroll
        for (int kk = 0; kk < 2; ++kk) {
          v8bf pb = *(const v8bf*)(Pb_h + (size_t)j * HD + kk * 32 + lg * 8);
          a = MFMA(qv2[kk], pb, a);
        }
        t2[n] = a;
      }
    }

    // ---- gather shift + logits ----
    #pragma unroll
    for (int kt4 = 0; kt4 < 4; ++kt4) {
      #pragma unroll
      for (int r = 0; r < 4; ++r) {
        int dq = lg * 4 + r;
        int dk = kt4 * 16 + lr;
        int cc = dk - dq + 15;                   // in [0, 30+kt4*16]
        int srcLane = (lane & 48) | (cc & 15);
        int hi = (cc >> 4) != kt4;
        float v1a = __shfl(t1[kt4][r],     srcLane, 64);
        float v1b = __shfl(t1[kt4 + 1][r], srcLane, 64);
        float v2a = __shfl(t2[kt4][r],     srcLane, 64);
        float v2b = __shfl(t2[kt4 + 1][r], srcLane, 64);
        float bd1 = hi ? v1b : v1a;
        float bd2 = hi ? v2b : v2a;
        int kg = k0 + dk, qg = q0 + dq;
        float bd = (kg <= qg) ? bd1 : ((kg == qg + 1) ? 0.f : bd2);
        s[kt4][r] = (s[kt4][r] + bd) * 0.125f;   // scale = hd^-0.5
      }
    }

    // ---- online softmax ----
    #pragma unroll
    for (int r = 0; r < 4; ++r) {
      float rmax = s[0][r];
      #pragma unroll
      for (int kt4 = 1; kt4 < 4; ++kt4) rmax = fmaxf(rmax, s[kt4][r]);
      #pragma unroll
      for (int off = 1; off < 16; off <<= 1)
        rmax = fmaxf(rmax, __shfl_xor(rmax, off, 64));
      float mnew  = fmaxf(m_r[r], rmax);
      float alpha = __expf(m_r[r] - mnew);
      m_r[r] = mnew;
      float rsum = 0.f;
      #pragma unroll
      for (int kt4 = 0; kt4 < 4; ++kt4) {
        float p = __expf(s[kt4][r] - mnew);
        s[kt4][r] = p;
        rsum += p;
      }
      #pragma unroll
      for (int off = 1; off < 16; off <<= 1)
        rsum += __shfl_xor(rsum, off, 64);
      l_r[r] = l_r[r] * alpha + rsum;
      #pragma unroll
      for (int n = 0; n < 4; ++n)
        o_acc[n][r] = o_acc[n][r] * alpha;
      #pragma unroll
      for (int kt4 = 0; kt4 < 4; ++kt4)
        Ps[wave][lg * 4 + r][kt4 * 16 + lr] = f2bf(s[kt4][r]);
    }
    asm volatile("s_waitcnt lgkmcnt(0)" ::: "memory");

    // ---- PV: O += P @ V ----
    #pragma unroll
    for (int kk = 0; kk < 2; ++kk) {
      v8bf pa = *(const v8bf*)(&Ps[wave][lr][kk * 32 + lg * 8]);
      #pragma unroll
      for (int n = 0; n < 4; ++n) {
        v8bf vb = *(const v8bf*)(&Vs[n * 16 + lr][kk * 32 + lg * 8]);
        o_acc[n] = MFMA(pa, vb, o_acc[n]);
      }
    }
  }

  // ---- normalize + write AO (B, L, H*HD) bf16 ----
  const int b = bh >> 4;
  #pragma unroll
  for (int r = 0; r < 4; ++r) {
    float inv = 1.0f / l_r[r];
    int q = q0 + lg * 4 + r;
    #pragma unroll
    for (int n = 0; n < 4; ++n) {
      int hd = n * 16 + lr;
      AO[((size_t)b * Lq + q) * Dm + h * HD + hd] = f2bf(o_acc[n][r] * inv);
    }
  }
}

// ---------------------------------------------------------------------------
extern "C" void kernel_launch(void* const* d_in, const int* in_sizes, int n_in,
                              void* d_out, int out_size, void* d_ws, size_t ws_size,
                              hipStream_t stream)
{
  (void)in_sizes; (void)n_in; (void)out_size; (void)ws_size;
  const float* x    = (const float*)d_in[0];
  const float* pos  = (const float*)d_in[1];
  const float* Wq   = (const float*)d_in[2];
  const float* bq   = (const float*)d_in[3];
  const float* Wk   = (const float*)d_in[4];
  const float* bk   = (const float*)d_in[5];
  const float* Wv   = (const float*)d_in[6];
  const float* bv   = (const float*)d_in[7];
  const float* Wpos = (const float*)d_in[8];
  const float* pu   = (const float*)d_in[9];
  const float* pvb  = (const float*)d_in[10];
  const float* Wo   = (const float*)d_in[11];
  const float* bo   = (const float*)d_in[12];
  float* out = (float*)d_out;

  // ws layout (bf16): Qu(4M) Qv(4M) Kb(4M) Vt(4M) Pb(2M) AO(4M) = 44 MB
  short* Qu = (short*)d_ws;
  short* Qv = Qu + (size_t)4 * 1024 * 1024;
  short* Kb = Qv + (size_t)4 * 1024 * 1024;
  short* Vt = Kb + (size_t)4 * 1024 * 1024;
  short* Pb = Vt + (size_t)4 * 1024 * 1024;
  short* AO = Pb + (size_t)2 * 1024 * 1024;

  dim3 blk(256);
  gemm_bt<0><<<dim3(8, 32), blk, 0, stream>>>(x,   Wq,   bq,      pu,      pvb,     Qu,  Qv);
  gemm_bt<1><<<dim3(8, 32), blk, 0, stream>>>(x,   Wk,   bk,      nullptr, nullptr, Kb,  nullptr);
  gemm_bt<2><<<dim3(8, 32), blk, 0, stream>>>(x,   Wv,   bv,      nullptr, nullptr, Vt,  nullptr);
  gemm_bt<3><<<dim3(8, 16), blk, 0, stream>>>(pos, Wpos, nullptr, nullptr, nullptr, Pb,  nullptr);
  attn_kernel<<<dim3(Lq / 64, 2 * Hh), blk, 0, stream>>>(Qu, Qv, Kb, Vt, Pb, AO);
  gemm_bt<4><<<dim3(8, 32), blk, 0, stream>>>(AO,  Wo,   bo,      nullptr, nullptr, out, nullptr);
}

// Round 3
// 397.015 us; speedup vs baseline: 1.4038x; 1.4038x over previous
//
#include <hip/hip_runtime.h>
#include <hip/hip_bf16.h>

// Problem constants
constexpr int Lq = 2048;   // sequence length
constexpr int Dm = 1024;   // model dim
constexpr int Hh = 16;     // heads
constexpr int HD = 64;     // head dim

typedef __bf16 v8bf __attribute__((ext_vector_type(8)));
typedef short  v4s  __attribute__((ext_vector_type(4)));
typedef float  v4f  __attribute__((ext_vector_type(4)));

#define DEV static __device__ __forceinline__

DEV short f2bf(float f) {
  return (short)__builtin_bit_cast(unsigned short, __float2bfloat16(f));
}

DEV v4f MFMA(v8bf a, v8bf b, v4f c) {
  return __builtin_amdgcn_mfma_f32_16x16x32_bf16(a, b, c, 0, 0, 0);
}

// DPP cross-lane (VALU pipe, not LDS): 16-lane reduce = xor1,xor2,half_mirror,mirror
template<int CTRL>
DEV float dppf(float x) {
  return __builtin_bit_cast(float, __builtin_amdgcn_update_dpp(
      0, __builtin_bit_cast(int, x), CTRL, 0xF, 0xF, true));
}
DEV float rowmax16(float x) {
  x = fmaxf(x, dppf<0xB1>(x));    // quad_perm [1,0,3,2]
  x = fmaxf(x, dppf<0x4E>(x));    // quad_perm [2,3,0,1]
  x = fmaxf(x, dppf<0x141>(x));   // row_half_mirror
  x = fmaxf(x, dppf<0x140>(x));   // row_mirror
  return x;
}
DEV float rowsum16(float x) {
  x += dppf<0xB1>(x);
  x += dppf<0x4E>(x);
  x += dppf<0x141>(x);
  x += dppf<0x140>(x);
  return x;
}

DEV float bperm(int byteaddr, float x) {
  return __builtin_bit_cast(float,
      __builtin_amdgcn_ds_bpermute(byteaddr, __builtin_bit_cast(int, x)));
}

#if __has_builtin(__builtin_amdgcn_exp2f)
DEV float exp2g(float x) { return __builtin_amdgcn_exp2f(x); }
#else
DEV float exp2g(float x) { return exp2f(x); }
#endif

DEV v4s cvt4(float4 v) {
  v4s w; w[0] = f2bf(v.x); w[1] = f2bf(v.y); w[2] = f2bf(v.z); w[3] = f2bf(v.w);
  return w;
}

// ---------------------------------------------------------------------------
// GEMM: C[i,o] = sum_k A[i,k] * W[o,k]  (+epilogue per MODE)
// A: fp32 (MODE 0..3) or bf16 (MODE 4), row-major MxK. W: fp32 NxK. K=N=1024.
// 64x64 tile, BK=64, 4 waves each 32x32 quadrant. grid (N/64, M/64).
// MODE 0: Q  -> Qu = y+bq+u and Qv = y+bq+v, (B,H,L,HD) bf16
// MODE 1: K  -> Kb (B,H,L,HD) bf16
// MODE 2: V  -> Vt (B,H,HD,L) bf16 (transposed)
// MODE 3: P  -> Pb (H,L,HD)  bf16 (no bias)
// MODE 4: O  -> d_out fp32 = A@Wo^T + bo
// ---------------------------------------------------------------------------
template<int MODE>
__launch_bounds__(256)
__global__ void gemm_bt(const void* __restrict__ Aptr,
                        const float* __restrict__ W,
                        const float* __restrict__ bias,
                        const float* __restrict__ ubias,
                        const float* __restrict__ vbias,
                        void* __restrict__ out0,
                        void* __restrict__ out1)
{
  __shared__ short As[64][72];   // +8 pad: conflict-free ds_read_b128
  __shared__ short Bs[64][72];

  const int tid  = threadIdx.x;
  const int lane = tid & 63;
  const int wave = tid >> 6;
  const int lr   = lane & 15;
  const int lg   = lane >> 4;
  const int row0 = blockIdx.y * 64;
  const int col0 = blockIdx.x * 64;
  const int wr   = (wave >> 1) * 32;
  const int wc   = (wave & 1) * 32;

  // staging: thread -> row tid>>2, 16 consecutive cols at (tid&3)*16
  const int srow = tid >> 2;
  const int scol = (tid & 3) * 16;

  v4f acc[2][2] = {};

  for (int k0 = 0; k0 < Dm; k0 += 64) {
    __syncthreads();
    if (MODE == 4) {
      const short* A = (const short*)Aptr;
      *(v8bf*)(&As[srow][scol]) =
          *(const v8bf*)(A + (size_t)(row0 + srow) * Dm + k0 + scol);
      *(v8bf*)(&As[srow][scol + 8]) =
          *(const v8bf*)(A + (size_t)(row0 + srow) * Dm + k0 + scol + 8);
    } else {
      const float* A = (const float*)Aptr;
      #pragma unroll
      for (int i = 0; i < 4; ++i) {
        float4 v = *(const float4*)(A + (size_t)(row0 + srow) * Dm + k0 + scol + i * 4);
        *(v4s*)(&As[srow][scol + i * 4]) = cvt4(v);
      }
    }
    #pragma unroll
    for (int i = 0; i < 4; ++i) {
      float4 v = *(const float4*)(W + (size_t)(col0 + srow) * Dm + k0 + scol + i * 4);
      *(v4s*)(&Bs[srow][scol + i * 4]) = cvt4(v);
    }
    __syncthreads();

    #pragma unroll
    for (int kk = 0; kk < 2; ++kk) {
      v8bf af[2], bfr[2];
      #pragma unroll
      for (int sm = 0; sm < 2; ++sm)
        af[sm] = *(const v8bf*)(&As[wr + sm * 16 + lr][kk * 32 + lg * 8]);
      #pragma unroll
      for (int sn = 0; sn < 2; ++sn)
        bfr[sn] = *(const v8bf*)(&Bs[wc + sn * 16 + lr][kk * 32 + lg * 8]);
      #pragma unroll
      for (int sm = 0; sm < 2; ++sm)
        #pragma unroll
        for (int sn = 0; sn < 2; ++sn)
          acc[sm][sn] = MFMA(af[sm], bfr[sn], acc[sm][sn]);
    }
  }

  // ---- epilogue (C frag: col = lane&15, row = (lane>>4)*4 + r) ----
  #pragma unroll
  for (int sm = 0; sm < 2; ++sm) {
    #pragma unroll
    for (int sn = 0; sn < 2; ++sn) {
      #pragma unroll
      for (int r = 0; r < 4; ++r) {
        int i = row0 + wr + sm * 16 + lg * 4 + r;
        int o = col0 + wc + sn * 16 + lr;
        float val = acc[sm][sn][r];
        if (MODE == 0) {
          val += bias[o];
          int b = i >> 11, l = i & 2047;
          int h = o >> 6,  hd = o & 63;
          size_t idx = (((size_t)(b * Hh + h)) * Lq + l) * HD + hd;
          ((short*)out0)[idx] = f2bf(val + ubias[o]);
          ((short*)out1)[idx] = f2bf(val + vbias[o]);
        } else if (MODE == 1) {
          val += bias[o];
          int b = i >> 11, l = i & 2047;
          int h = o >> 6,  hd = o & 63;
          size_t idx = (((size_t)(b * Hh + h)) * Lq + l) * HD + hd;
          ((short*)out0)[idx] = f2bf(val);
        } else if (MODE == 2) {
          val += bias[o];
          int b = i >> 11, l = i & 2047;
          int h = o >> 6,  hd = o & 63;
          size_t idx = (((size_t)(b * Hh + h)) * HD + hd) * Lq + l;
          ((short*)out0)[idx] = f2bf(val);
        } else if (MODE == 3) {
          int h = o >> 6, hd = o & 63;
          size_t idx = ((size_t)h * Lq + i) * HD + hd;
          ((short*)out0)[idx] = f2bf(val);
        } else {
          ((float*)out0)[(size_t)i * Dm + o] = val + bias[o];
        }
      }
    }
  }
}

// ---------------------------------------------------------------------------
// Fused rel-pos flash attention.
// grid (L/64, B*H), block 256 (4 waves, each a 16-row q-strip).
// rel_shift closed form:
//   k <= q   : bd[q,   L-1-q+k]
//   k == q+1 : 0
//   k >  q+1 : bd[q+1, k-q-2]        (row-wrap artifact of the reshape trick)
// T1/T2 = banded (Qv @ P_band^T) MFMAs. Branch selection depends only on the
// absolute band position cc, so T1/T2/0 is selected at the SOURCE lane before
// the gather (1 cndmask + 2 bpermute per element, addr/hi hoisted & loop-
// invariant). Softmax row-reduces run on DPP (VALU pipe).
// ---------------------------------------------------------------------------
__launch_bounds__(256)
__global__ void attn_kernel(const short* __restrict__ Qu,
                            const short* __restrict__ Qv,
                            const short* __restrict__ Kb,
                            const short* __restrict__ Vt,
                            const short* __restrict__ Pb,
                            short* __restrict__ AO)
{
  __shared__ short Ks[64][72];      // K tile: rows=k, cols=hd
  __shared__ short Vs[64][72];      // V^T tile: rows=hd, cols=k
  __shared__ short Ps[4][16][72];   // per-wave softmax probs (bf16)

  const int tid  = threadIdx.x;
  const int lane = tid & 63;
  const int wave = tid >> 6;
  const int lr   = lane & 15;
  const int lg   = lane >> 4;
  const int bh   = blockIdx.y;          // b*H + h
  const int h    = bh & (Hh - 1);
  const int Q0   = blockIdx.x * 64;
  const int q0   = Q0 + wave * 16;

  const short* Qu_bh = Qu + (size_t)bh * Lq * HD;
  const short* Qv_bh = Qv + (size_t)bh * Lq * HD;
  const short* Kb_bh = Kb + (size_t)bh * Lq * HD;
  const short* Vt_bh = Vt + (size_t)bh * HD * Lq;
  const short* Pb_h  = Pb + (size_t)h * Lq * HD;

  // hoisted gather constants: cc = kt4*16 + c, c = lr - dq + 15 in [0,30]
  int  addr4[4];
  bool hi4[4];
  #pragma unroll
  for (int r = 0; r < 4; ++r) {
    int c = lr - (lg * 4 + r) + 15;
    hi4[r]  = (c >= 16);
    addr4[r] = (((lane & 48) | (c & 15)) << 2);
  }

  // Q fragments (A operand): lane holds row (q0+lr), k = kk*32 + lg*8 + e
  v8bf qu[2], qv1[2], qv2[2];
  {
    int q  = q0 + lr;
    int q2 = (q + 1 < Lq) ? q + 1 : Lq - 1;   // clamped row never selected
    #pragma unroll
    for (int kk = 0; kk < 2; ++kk) {
      qu[kk]  = *(const v8bf*)(Qu_bh + (size_t)q  * HD + kk * 32 + lg * 8);
      qv1[kk] = *(const v8bf*)(Qv_bh + (size_t)q  * HD + kk * 32 + lg * 8);
      qv2[kk] = *(const v8bf*)(Qv_bh + (size_t)q2 * HD + kk * 32 + lg * 8);
    }
  }

  // K/V staging: thread -> row tid>>2, 16 cols at (tid&3)*16 (2 v8bf each)
  const int srow = tid >> 2;
  const int scol = (tid & 3) * 16;

  // async prefetch of tile 0
  v8bf kpre0 = *(const v8bf*)(Kb_bh + (size_t)srow * HD + scol);
  v8bf kpre1 = *(const v8bf*)(Kb_bh + (size_t)srow * HD + scol + 8);
  v8bf vpre0 = *(const v8bf*)(Vt_bh + (size_t)srow * Lq + scol);
  v8bf vpre1 = *(const v8bf*)(Vt_bh + (size_t)srow * Lq + scol + 8);

  float m_r[4], l_r[4];
  v4f o_acc[4];
  #pragma unroll
  for (int r = 0; r < 4; ++r) { m_r[r] = -1e30f; l_r[r] = 0.f; }
  #pragma unroll
  for (int n = 0; n < 4; ++n) o_acc[n] = v4f{0.f, 0.f, 0.f, 0.f};

  const float sc = 0.125f * 1.44269504088896f;   // hd^-0.5 * log2(e)

  for (int ktile = 0; ktile < Lq / 64; ++ktile) {
    const int k0 = ktile * 64;
    __syncthreads();                       // readers of previous tile done
    *(v8bf*)(&Ks[srow][scol])     = kpre0;
    *(v8bf*)(&Ks[srow][scol + 8]) = kpre1;
    *(v8bf*)(&Vs[srow][scol])     = vpre0;
    *(v8bf*)(&Vs[srow][scol + 8]) = vpre1;
    __syncthreads();                       // tile ready
    if (ktile + 1 < Lq / 64) {             // issue next-tile loads now;
      const int kn = k0 + 64;              // vmcnt waited at next ds_write
      kpre0 = *(const v8bf*)(Kb_bh + (size_t)(kn + srow) * HD + scol);
      kpre1 = *(const v8bf*)(Kb_bh + (size_t)(kn + srow) * HD + scol + 8);
      vpre0 = *(const v8bf*)(Vt_bh + (size_t)srow * Lq + kn + scol);
      vpre1 = *(const v8bf*)(Vt_bh + (size_t)srow * Lq + kn + scol + 8);
    }

    // ---- ac = Qu @ K^T  (16 x 64) ----
    v4f s[4];
    #pragma unroll
    for (int kt4 = 0; kt4 < 4; ++kt4) {
      v4f a = v4f{0.f, 0.f, 0.f, 0.f};
      #pragma unroll
      for (int kk = 0; kk < 2; ++kk) {
        v8bf kb = *(const v8bf*)(&Ks[kt4 * 16 + lr][kk * 32 + lg * 8]);
        a = MFMA(qu[kk], kb, a);
      }
      s[kt4] = a;
    }

    // ---- banded bd: T1 (rows q), T2 (rows q+1) ----
    const int thr = q0 - k0 + 15;          // select t1 iff cc <= thr
    const bool needT1 = (thr >= 0);
    const bool needT2 = (thr <= 76);
    const int jb1 = 2032 + k0 - q0;        // (Lq-1) - q0 + k0 - 15
    const int jb2 = k0 - q0 - 17;
    v4f t1[5] = {}, t2[5] = {};
    if (needT1) {
      #pragma unroll
      for (int n = 0; n < 5; ++n) {
        if (n * 16 <= thr) {               // band sub-tile live?
          int j = jb1 + n * 16 + lr;
          j = j < 0 ? 0 : (j > Lq - 1 ? Lq - 1 : j);
          v4f a = v4f{0.f, 0.f, 0.f, 0.f};
          #pragma unroll
          for (int kk = 0; kk < 2; ++kk) {
            v8bf pb = *(const v8bf*)(Pb_h + (size_t)j * HD + kk * 32 + lg * 8);
            a = MFMA(qv1[kk], pb, a);
          }
          t1[n] = a;
        }
      }
    }
    if (needT2) {
      #pragma unroll
      for (int n = 0; n < 5; ++n) {
        if (n * 16 + 15 >= thr + 2) {
          int j = jb2 + n * 16 + lr;
          j = j < 0 ? 0 : (j > Lq - 1 ? Lq - 1 : j);
          v4f a = v4f{0.f, 0.f, 0.f, 0.f};
          #pragma unroll
          for (int kk = 0; kk < 2; ++kk) {
            v8bf pb = *(const v8bf*)(Pb_h + (size_t)j * HD + kk * 32 + lg * 8);
            a = MFMA(qv2[kk], pb, a);
          }
          t2[n] = a;
        }
      }
    }

    // ---- source-side select (depends only on cc = n*16 + lr) ----
    #pragma unroll
    for (int n = 0; n < 5; ++n) {
      int cc = n * 16 + lr;
      #pragma unroll
      for (int r = 0; r < 4; ++r) {
        float v = (cc <= thr) ? t1[n][r] : ((cc == thr + 1) ? 0.f : t2[n][r]);
        t1[n][r] = v;
      }
    }

    // ---- gather (2 bpermute + 1 cndmask per element) + scaled logits ----
    #pragma unroll
    for (int kt4 = 0; kt4 < 4; ++kt4) {
      #pragma unroll
      for (int r = 0; r < 4; ++r) {
        float va = bperm(addr4[r], t1[kt4][r]);
        float vb = bperm(addr4[r], t1[kt4 + 1][r]);
        float bd = hi4[r] ? vb : va;
        s[kt4][r] = (s[kt4][r] + bd) * sc;
      }
    }

    // ---- online softmax (exp2 domain, DPP reduces) ----
    #pragma unroll
    for (int r = 0; r < 4; ++r) {
      float rmax = fmaxf(fmaxf(s[0][r], s[1][r]), fmaxf(s[2][r], s[3][r]));
      rmax = rowmax16(rmax);
      float mnew  = fmaxf(m_r[r], rmax);
      float alpha = exp2g(m_r[r] - mnew);
      m_r[r] = mnew;
      float rsum = 0.f;
      #pragma unroll
      for (int kt4 = 0; kt4 < 4; ++kt4) {
        float p = exp2g(s[kt4][r] - mnew);
        s[kt4][r] = p;
        rsum += p;
      }
      rsum = rowsum16(rsum);
      l_r[r] = l_r[r] * alpha + rsum;
      #pragma unroll
      for (int n = 0; n < 4; ++n)
        o_acc[n][r] = o_acc[n][r] * alpha;
      #pragma unroll
      for (int kt4 = 0; kt4 < 4; ++kt4)
        Ps[wave][lg * 4 + r][kt4 * 16 + lr] = f2bf(s[kt4][r]);
    }
    asm volatile("s_waitcnt lgkmcnt(0)" ::: "memory");
    __builtin_amdgcn_sched_barrier(0);

    // ---- PV: O += P @ V ----
    #pragma unroll
    for (int kk = 0; kk < 2; ++kk) {
      v8bf pa = *(const v8bf*)(&Ps[wave][lr][kk * 32 + lg * 8]);
      #pragma unroll
      for (int n = 0; n < 4; ++n) {
        v8bf vb = *(const v8bf*)(&Vs[n * 16 + lr][kk * 32 + lg * 8]);
        o_acc[n] = MFMA(pa, vb, o_acc[n]);
      }
    }
  }

  // ---- normalize + write AO (B, L, H*HD) bf16 ----
  const int b = bh >> 4;
  #pragma unroll
  for (int r = 0; r < 4; ++r) {
    float inv = 1.0f / l_r[r];
    int q = q0 + lg * 4 + r;
    #pragma unroll
    for (int n = 0; n < 4; ++n) {
      int hd = n * 16 + lr;
      AO[((size_t)b * Lq + q) * Dm + h * HD + hd] = f2bf(o_acc[n][r] * inv);
    }
  }
}

// ---------------------------------------------------------------------------
extern "C" void kernel_launch(void* const* d_in, const int* in_sizes, int n_in,
                              void* d_out, int out_size, void* d_ws, size_t ws_size,
                              hipStream_t stream)
{
  (void)in_sizes; (void)n_in; (void)out_size; (void)ws_size;
  const float* x    = (const float*)d_in[0];
  const float* pos  = (const float*)d_in[1];
  const float* Wq   = (const float*)d_in[2];
  const float* bq   = (const float*)d_in[3];
  const float* Wk   = (const float*)d_in[4];
  const float* bk   = (const float*)d_in[5];
  const float* Wv   = (const float*)d_in[6];
  const float* bv   = (const float*)d_in[7];
  const float* Wpos = (const float*)d_in[8];
  const float* pu   = (const float*)d_in[9];
  const float* pvb  = (const float*)d_in[10];
  const float* Wo   = (const float*)d_in[11];
  const float* bo   = (const float*)d_in[12];
  float* out = (float*)d_out;

  // ws layout (bf16): Qu(4M) Qv(4M) Kb(4M) Vt(4M) Pb(2M) AO(4M) elems = 44 MB
  short* Qu = (short*)d_ws;
  short* Qv = Qu + (size_t)4 * 1024 * 1024;
  short* Kb = Qv + (size_t)4 * 1024 * 1024;
  short* Vt = Kb + (size_t)4 * 1024 * 1024;
  short* Pb = Vt + (size_t)4 * 1024 * 1024;
  short* AO = Pb + (size_t)2 * 1024 * 1024;

  dim3 blk(256);
  gemm_bt<0><<<dim3(16, 64), blk, 0, stream>>>(x,   Wq,   bq,      pu,      pvb,     Qu,  Qv);
  gemm_bt<1><<<dim3(16, 64), blk, 0, stream>>>(x,   Wk,   bk,      nullptr, nullptr, Kb,  nullptr);
  gemm_bt<2><<<dim3(16, 64), blk, 0, stream>>>(x,   Wv,   bv,      nullptr, nullptr, Vt,  nullptr);
  gemm_bt<3><<<dim3(16, 32), blk, 0, stream>>>(pos, Wpos, nullptr, nullptr, nullptr, Pb,  nullptr);
  attn_kernel<<<dim3(Lq / 64, 2 * Hh), blk, 0, stream>>>(Qu, Qv, Kb, Vt, Pb, AO);
  gemm_bt<4><<<dim3(16, 64), blk, 0, stream>>>(AO,  Wo,   bo,      nullptr, nullptr, out, nullptr);
}